// Round 5
// baseline (194.007 us; speedup 1.0000x reference)
//
#include <hip/hip_runtime.h>
#include <hip/hip_cooperative_groups.h>

namespace cg = cooperative_groups;

#define EPS 1e-4f

constexpr int B  = 8;
constexpr int C  = 128;
constexpr int Tt = 9;
constexpr int T  = 8;
constexpr int H  = 64;
constexpr int W  = 64;
constexpr int HW = H * W;          // 4096
constexpr int HM = 256;
constexpr int WM = 256;
constexpr int HWM = HM * WM;       // 65536

typedef __attribute__((ext_vector_type(4))) float f32x4;

// ws layout (float offsets). Every cell is written before read on every
// replay — no cross-replay state, no zero-init needed.
constexpr int WS_TV  = 0;                      // B*HW      = 32768
constexpr int WS_RV  = WS_TV + B * HW;         // B*T*HW    = 262144
constexpr int WS_GSP = WS_RV + B * T * HW;     // gs partials [b][cc*4+hq][t]
constexpr int WS_VSP = WS_GSP + B * 64 * T;    // vs partials [b][hq][t]

__device__ __forceinline__ const f32x4& ld4(const float* p) {
  return *reinterpret_cast<const f32x4*>(p);
}
__device__ __forceinline__ void st4(float* p, f32x4 v) {
  *reinterpret_cast<f32x4*>(p) = v;
}

// --- antialiased bilinear downsample 256 -> 64 (scale 1/4), one output pixel.
// jax.image.resize 'bilinear' antialias=True: sample = 4o+1.5, taps 4o-2..4o+5,
// unnormalized weights {1,3,5,7,7,5,3,1}, per-dim renormalized over valid taps.
__device__ __forceinline__ float resample_px(const float* __restrict__ src,
                                             int y, int x) {
  const float wt[8] = {1.f, 3.f, 5.f, 7.f, 7.f, 5.f, 3.f, 1.f};
  int by = 4 * y - 2, bx = 4 * x - 2;
  float wx[8];
  float nx = 0.f;
  #pragma unroll
  for (int d = 0; d < 8; ++d) {
    int xx = bx + d;
    float w = (xx >= 0 && xx < WM) ? wt[d] : 0.f;
    wx[d] = w;
    nx += w;
  }
  float ny = 0.f;
  float sum = 0.f;
  #pragma unroll
  for (int dy = 0; dy < 8; ++dy) {
    int yy = by + dy;
    if (yy < 0 || yy >= HM) continue;
    ny += wt[dy];
    const float* row = src + yy * WM;
    float rowsum = 0.f;
    #pragma unroll
    for (int dx = 0; dx < 8; ++dx) {
      int xx = bx + dx;
      xx = xx < 0 ? 0 : (xx >= WM ? WM - 1 : xx);  // clamp addr; weight 0 if OOB
      rowsum += wx[dx] * row[xx];
    }
    sum += wt[dy] * rowsum;
  }
  return sum / (ny * nx);
}

// One cooperative kernel, 512 blocks x 256 threads (guaranteed 2 blocks/CU).
// Phase 0: masks. Phase 1: gs partials (values pass 1, cold HBM).
// Phase 2: finalize + softmax + outputs (values pass 2, L3-warm).
__global__ __launch_bounds__(256, 2) void fused_kernel(
    const float* __restrict__ values, const float* __restrict__ tvmap,
    const float* __restrict__ rvmaps, float* __restrict__ out,
    float* __restrict__ ws) {
  cg::grid_group grid = cg::this_grid();
  int tid = threadIdx.x;
  int bid = blockIdx.x;

  // ---------- phase 0: masks (72 maps * 4096 px, grid-strided) ----------
  {
    int gtid = bid * 256 + tid;
    constexpr int TOTAL = (B + B * T) * HW;  // 294912
    for (int p = gtid; p < TOTAL; p += 512 * 256) {
      int m = p >> 12;
      int px = p & (HW - 1);
      int y = px >> 6, x = px & 63;
      const float* src;
      float* dst;
      if (m < B) {
        src = tvmap + (size_t)m * HWM;
        dst = ws + WS_TV + m * HW;
      } else {
        src = rvmaps + (size_t)(m - B) * HWM;
        dst = ws + WS_RV + (m - B) * HW;
      }
      float v = resample_px(src, y, x);
      dst[px] = (v > 0.5f) ? 1.f : 0.f;
    }
  }
  grid.sync();

  // ---------- phase 1: gs partials ----------
  int hq = bid & 3, cc = (bid >> 2) & 15, b = bid >> 6;
  int px = hq * 1024 + tid * 4;
  int lane = tid & 63, wave = tid >> 6;
  __shared__ float red[4][T];
  {
    f32x4 tv = ld4(ws + WS_TV + b * HW + px);
    f32x4 vm[T];
    #pragma unroll
    for (int t = 0; t < T; ++t)
      vm[t] = tv * ld4(ws + WS_RV + (b * T + t) * HW + px);

    float acc[T];
    #pragma unroll
    for (int t = 0; t < T; ++t) acc[t] = 0.f;

    const float* vb = values + (size_t)(b * C + cc * 8) * Tt * HW;
    #pragma unroll 2
    for (int c = 0; c < 8; ++c) {
      const float* vc = vb + (size_t)c * Tt * HW;
      f32x4 tf = ld4(vc + px);
      #pragma unroll
      for (int t = 0; t < T; ++t) {
        f32x4 rf = ld4(vc + (t + 1) * HW + px);
        #pragma unroll
        for (int j = 0; j < 4; ++j) acc[t] += tf[j] * rf[j] * vm[t][j];
      }
    }

    #pragma unroll
    for (int t = 0; t < T; ++t) {
      float v = acc[t];
      #pragma unroll
      for (int m = 32; m > 0; m >>= 1) v += __shfl_xor(v, m);
      if (lane == 0) red[wave][t] = v;
    }
    __syncthreads();
    if (tid < T) {
      float s = red[0][tid] + red[1][tid] + red[2][tid] + red[3][tid];
      ws[WS_GSP + ((b * 16 + cc) * 4 + hq) * T + tid] = s;
    }

    if (cc == 0) {
      __syncthreads();
      #pragma unroll
      for (int t = 0; t < T; ++t) {
        float v = vm[t][0] + vm[t][1] + vm[t][2] + vm[t][3];
        #pragma unroll
        for (int m = 32; m > 0; m >>= 1) v += __shfl_xor(v, m);
        if (lane == 0) red[wave][t] = v;
      }
      __syncthreads();
      if (tid < T) {
        float s = red[0][tid] + red[1][tid] + red[2][tid] + red[3][tid];
        ws[WS_VSP + (b * 4 + hq) * T + tid] = s;
      }
    }
  }
  grid.sync();

  // ---------- phase 2: finalize gs + softmax + t_feat + c_out + c_mask ----
  __shared__ float gsf_sh[T];
  if (tid < 64) {
    int t = tid >> 3, part = tid & 7;
    float s = 0.f;
    #pragma unroll
    for (int k = 0; k < 8; ++k)
      s += ws[WS_GSP + (b * 64 + part * 8 + k) * T + t];
    #pragma unroll
    for (int m = 1; m < 8; m <<= 1) s += __shfl_xor(s, m);
    if (part == 0) {
      float vs = 0.f;
      #pragma unroll
      for (int h = 0; h < 4; ++h) vs += ws[WS_VSP + (b * 4 + h) * T + t];
      bool zero = vs < EPS;           // vs is an exact integer-valued count
      float g = zero ? 0.f : s;
      vs += zero ? 1.f : 0.f;
      gsf_sh[t] = g / vs / (float)C;
    }
  }
  __syncthreads();

  float gsf[T];
  #pragma unroll
  for (int t = 0; t < T; ++t) gsf[t] = gsf_sh[t];

  f32x4 rv[T], cm[T];
  #pragma unroll
  for (int t = 0; t < T; ++t)
    rv[t] = ld4(ws + WS_RV + (b * T + t) * HW + px);

  // masked_vec = gsf*rv (zeros where rv=0 participate in the max)
  f32x4 mx = gsf[0] * rv[0];
  #pragma unroll
  for (int t = 1; t < T; ++t) {
    #pragma unroll
    for (int j = 0; j < 4; ++j) mx[j] = fmaxf(mx[j], gsf[t] * rv[t][j]);
  }
  f32x4 s = {0.f, 0.f, 0.f, 0.f};
  #pragma unroll
  for (int t = 0; t < T; ++t) {
    #pragma unroll
    for (int j = 0; j < 4; ++j)
      cm[t][j] = expf(gsf[t] * rv[t][j] - mx[j]) * rv[t][j];
    s += cm[t];
  }
  #pragma unroll
  for (int j = 0; j < 4; ++j) {
    s[j] += (s[j] < EPS) ? 1.f : 0.f;
    s[j] = 1.f / s[j];
  }
  f32x4 csum = {0.f, 0.f, 0.f, 0.f};
  #pragma unroll
  for (int t = 0; t < T; ++t) {
    cm[t] *= s;
    csum += cm[t];
  }

  if (cc == 0) {
    f32x4 cmask;
    #pragma unroll
    for (int j = 0; j < 4; ++j) cmask[j] = 1.f - csum[j];
    st4(out + ((size_t)b * 257 + 256) * HW + px, cmask);
    st4(out + (size_t)B * 257 * HW + (size_t)b * HW + px, cmask);
  }

  // channels in REVERSE of phase 1 so the block's most-recently-read L2
  // lines are consumed first.
  const float* vb = values + (size_t)(b * C + cc * 8) * Tt * HW;
  #pragma unroll 2
  for (int c = 7; c >= 0; --c) {
    const float* vc = vb + (size_t)c * Tt * HW;
    f32x4 tf = ld4(vc + px);
    st4(out + ((size_t)b * 257 + cc * 8 + c) * HW + px, tf);  // t_feat copy
    f32x4 acc = {0.f, 0.f, 0.f, 0.f};
    #pragma unroll
    for (int t = 0; t < T; ++t) {
      f32x4 rf = ld4(vc + (t + 1) * HW + px);
      acc += rf * cm[t];
    }
    st4(out + ((size_t)b * 257 + 128 + cc * 8 + c) * HW + px, acc);
  }
}

extern "C" void kernel_launch(void* const* d_in, const int* in_sizes, int n_in,
                              void* d_out, int out_size, void* d_ws, size_t ws_size,
                              hipStream_t stream) {
  const float* values = (const float*)d_in[0];
  const float* tvmap  = (const float*)d_in[1];
  const float* rvmaps = (const float*)d_in[2];
  float* out = (float*)d_out;
  float* ws  = (float*)d_ws;

  void* args[] = {(void*)&values, (void*)&tvmap, (void*)&rvmaps,
                  (void*)&out, (void*)&ws};
  hipLaunchCooperativeKernel((void*)fused_kernel, dim3(512), dim3(256),
                             args, 0, stream);
}

// Round 6
// 83.184 us; speedup vs baseline: 2.3323x; 2.3323x over previous
//
#include <hip/hip_runtime.h>

#define EPS 1e-4f

constexpr int B  = 8;
constexpr int C  = 128;
constexpr int Tt = 9;
constexpr int T  = 8;
constexpr int H  = 64;
constexpr int W  = 64;
constexpr int HW = H * W;          // 4096
constexpr int HM = 256;
constexpr int WM = 256;
constexpr int HWM = HM * WM;       // 65536

typedef __attribute__((ext_vector_type(4))) float f32x4;

// ws layout (float offsets). Every cell written before read each replay.
constexpr int WS_TV  = 0;                      // B*HW      = 32768
constexpr int WS_RV  = WS_TV + B * HW;         // B*T*HW    = 262144
constexpr int WS_GSP = WS_RV + B * T * HW;     // gs partials [b][c2(64)][t]
constexpr int WS_VSP = WS_GSP + B * 64 * T;    // vs partials [b][t]

__device__ __forceinline__ const f32x4& ld4(const float* p) {
  return *reinterpret_cast<const f32x4*>(p);
}
__device__ __forceinline__ void st4(float* p, f32x4 v) {
  *reinterpret_cast<f32x4*>(p) = v;
}

// --- antialiased bilinear downsample 256 -> 64 (scale 1/4), one output pixel.
// jax.image.resize 'bilinear' antialias=True: sample = 4o+1.5, taps 4o-2..4o+5,
// unnormalized weights {1,3,5,7,7,5,3,1}, per-dim renormalized over valid taps.
__device__ __forceinline__ float resample_px(const float* __restrict__ src,
                                             int y, int x) {
  const float wt[8] = {1.f, 3.f, 5.f, 7.f, 7.f, 5.f, 3.f, 1.f};
  int by = 4 * y - 2, bx = 4 * x - 2;
  float wx[8];
  float nx = 0.f;
  #pragma unroll
  for (int d = 0; d < 8; ++d) {
    int xx = bx + d;
    float w = (xx >= 0 && xx < WM) ? wt[d] : 0.f;
    wx[d] = w;
    nx += w;
  }
  float ny = 0.f;
  float sum = 0.f;
  #pragma unroll
  for (int dy = 0; dy < 8; ++dy) {
    int yy = by + dy;
    if (yy < 0 || yy >= HM) continue;
    ny += wt[dy];
    const float* row = src + yy * WM;
    float rowsum = 0.f;
    #pragma unroll
    for (int dx = 0; dx < 8; ++dx) {
      int xx = bx + dx;
      xx = xx < 0 ? 0 : (xx >= WM ? WM - 1 : xx);  // clamp addr; weight 0 if OOB
      rowsum += wx[dx] * row[xx];
    }
    sum += wt[dy] * rowsum;
  }
  return sum / (ny * nx);
}

// Kernel A: masks, grid-strided over all 72 maps * 4096 px.
__global__ __launch_bounds__(256) void mask_kernel(
    const float* __restrict__ tvmap, const float* __restrict__ rvmaps,
    float* __restrict__ ws) {
  int gtid = blockIdx.x * 256 + threadIdx.x;
  constexpr int TOTAL = (B + B * T) * HW;  // 294912
  for (int p = gtid; p < TOTAL; p += 512 * 256) {
    int m = p >> 12;          // map index 0..71
    int px = p & (HW - 1);
    int y = px >> 6, x = px & 63;
    const float* src;
    float* dst;
    if (m < B) {
      src = tvmap + (size_t)m * HWM;
      dst = ws + WS_TV + m * HW;
    } else {
      src = rvmaps + (size_t)(m - B) * HWM;
      dst = ws + WS_RV + (m - B) * HW;
    }
    float v = resample_px(src, y, x);
    dst[px] = (v > 0.5f) ? 1.f : 0.f;
  }
}

// Kernel B: gs partials with STRICTLY LINEAR global reads.
// 512 blocks (b x c2), 2 whole channels per block = 294 KB contiguous stream.
// Masks staged as bytes in LDS, tf plane staged in LDS, plane index
// compile-time (full unroll) so acc[] stays in registers.
__global__ __launch_bounds__(256) void gs_kernel(
    const float* __restrict__ values, float* __restrict__ ws) {
  int bid = blockIdx.x;
  int c2 = bid & 63, b = bid >> 6;
  int tid = threadIdx.x;

  __shared__ unsigned char vmb[T][HW];   // 32 KB
  __shared__ float tfs[HW];              // 16 KB
  __shared__ float red[4][T];

  // ---- build vm bytes (and vs counts on c2==0 blocks) ----
  int vs_local[T];
  #pragma unroll
  for (int t = 0; t < T; ++t) vs_local[t] = 0;

  const float* tvp = ws + WS_TV + b * HW;
  const float* rvp = ws + WS_RV + b * T * HW;
  #pragma unroll
  for (int p = 0; p < T; ++p) {
    #pragma unroll
    for (int qt = 0; qt < 4; ++qt) {
      int px = qt * 1024 + tid * 4;
      f32x4 tv = ld4(tvp + px);
      f32x4 rv = ld4(rvp + p * HW + px);
      uchar4 u;
      u.x = (tv[0] * rv[0] > 0.5f);
      u.y = (tv[1] * rv[1] > 0.5f);
      u.z = (tv[2] * rv[2] > 0.5f);
      u.w = (tv[3] * rv[3] > 0.5f);
      *reinterpret_cast<uchar4*>(&vmb[p][px]) = u;
      vs_local[p] += u.x + u.y + u.z + u.w;
    }
  }
  __syncthreads();

  int lane = tid & 63, wave = tid >> 6;
  if (c2 == 0) {
    #pragma unroll
    for (int t = 0; t < T; ++t) {
      float v = (float)vs_local[t];
      #pragma unroll
      for (int m = 32; m > 0; m >>= 1) v += __shfl_xor(v, m);
      if (lane == 0) red[wave][t] = v;
    }
    __syncthreads();
    if (tid < T)
      ws[WS_VSP + b * T + tid] =
          red[0][tid] + red[1][tid] + red[2][tid] + red[3][tid];
    __syncthreads();
  }

  // ---- two channels, each walked linearly front-to-back ----
  float acc[T];
  #pragma unroll
  for (int t = 0; t < T; ++t) acc[t] = 0.f;

  const float* vb = values + (size_t)(b * C + c2 * 2) * Tt * HW;
  #pragma unroll 1
  for (int ci = 0; ci < 2; ++ci) {
    const float* vc = vb + (size_t)ci * Tt * HW;
    // stage tf plane (first 16 KB of the channel, linear)
    #pragma unroll
    for (int qt = 0; qt < 4; ++qt) {
      int px = qt * 1024 + tid * 4;
      st4(&tfs[px], ld4(vc + px));
    }
    __syncthreads();
    // rf planes 1..8, linear continuation of the same stream
    #pragma unroll
    for (int p = 1; p <= Tt - 1; ++p) {
      #pragma unroll
      for (int qt = 0; qt < 4; ++qt) {
        int px = qt * 1024 + tid * 4;
        f32x4 rf = ld4(vc + p * HW + px);
        f32x4 tf = *reinterpret_cast<const f32x4*>(&tfs[px]);
        uchar4 u = *reinterpret_cast<const uchar4*>(&vmb[p - 1][px]);
        acc[p - 1] += (u.x ? tf[0] * rf[0] : 0.f) +
                      (u.y ? tf[1] * rf[1] : 0.f) +
                      (u.z ? tf[2] * rf[2] : 0.f) +
                      (u.w ? tf[3] * rf[3] : 0.f);
      }
    }
    __syncthreads();   // protect tfs before next channel restages
  }

  #pragma unroll
  for (int t = 0; t < T; ++t) {
    float v = acc[t];
    #pragma unroll
    for (int m = 32; m > 0; m >>= 1) v += __shfl_xor(v, m);
    if (lane == 0) red[wave][t] = v;
  }
  __syncthreads();
  if (tid < T)
    ws[WS_GSP + (b * 64 + c2) * T + tid] =
        red[0][tid] + red[1][tid] + red[2][tid] + red[3][tid];
}

// Kernel C: finalize gs (redundant, tiny) + per-px softmax + t_feat copy +
// c_out + c_mask. 512 blocks = b(8) x cc(16) x hq(4); values reads L3-hot.
__global__ __launch_bounds__(256) void out_kernel(
    const float* __restrict__ values, const float* __restrict__ ws,
    float* __restrict__ out) {
  int bid = blockIdx.x;
  int hq = bid & 3, cc = (bid >> 2) & 15, b = bid >> 6;
  int tid = threadIdx.x;
  int px = hq * 1024 + tid * 4;

  __shared__ float gsf_sh[T];
  if (tid < 64) {
    int t = tid >> 3, part = tid & 7;
    float s = 0.f;
    #pragma unroll
    for (int k = 0; k < 8; ++k)
      s += ws[WS_GSP + (b * 64 + part * 8 + k) * T + t];
    #pragma unroll
    for (int m = 1; m < 8; m <<= 1) s += __shfl_xor(s, m);
    if (part == 0) {
      float vs = ws[WS_VSP + b * T + t];  // exact integer-valued count
      bool zero = vs < EPS;
      float g = zero ? 0.f : s;
      vs += zero ? 1.f : 0.f;
      gsf_sh[t] = g / vs / (float)C;
    }
  }
  __syncthreads();

  float gsf[T];
  #pragma unroll
  for (int t = 0; t < T; ++t) gsf[t] = gsf_sh[t];

  f32x4 rv[T], cm[T];
  #pragma unroll
  for (int t = 0; t < T; ++t)
    rv[t] = ld4(ws + WS_RV + (b * T + t) * HW + px);

  // masked_vec = gsf*rv (zeros where rv=0 participate in the max)
  f32x4 mx = gsf[0] * rv[0];
  #pragma unroll
  for (int t = 1; t < T; ++t) {
    #pragma unroll
    for (int j = 0; j < 4; ++j) mx[j] = fmaxf(mx[j], gsf[t] * rv[t][j]);
  }
  f32x4 s = {0.f, 0.f, 0.f, 0.f};
  #pragma unroll
  for (int t = 0; t < T; ++t) {
    #pragma unroll
    for (int j = 0; j < 4; ++j)
      cm[t][j] = expf(gsf[t] * rv[t][j] - mx[j]) * rv[t][j];
    s += cm[t];
  }
  #pragma unroll
  for (int j = 0; j < 4; ++j) {
    s[j] += (s[j] < EPS) ? 1.f : 0.f;
    s[j] = 1.f / s[j];
  }
  f32x4 csum = {0.f, 0.f, 0.f, 0.f};
  #pragma unroll
  for (int t = 0; t < T; ++t) {
    cm[t] *= s;
    csum += cm[t];
  }

  if (cc == 0) {
    f32x4 cmask;
    #pragma unroll
    for (int j = 0; j < 4; ++j) cmask[j] = 1.f - csum[j];
    st4(out + ((size_t)b * 257 + 256) * HW + px, cmask);
    st4(out + (size_t)B * 257 * HW + (size_t)b * HW + px, cmask);
  }

  const float* vb = values + (size_t)(b * C + cc * 8) * Tt * HW;
  #pragma unroll 2
  for (int c = 0; c < 8; ++c) {
    const float* vc = vb + (size_t)c * Tt * HW;
    f32x4 tf = ld4(vc + px);
    st4(out + ((size_t)b * 257 + cc * 8 + c) * HW + px, tf);  // t_feat copy
    f32x4 acc = {0.f, 0.f, 0.f, 0.f};
    #pragma unroll
    for (int t = 0; t < T; ++t) {
      f32x4 rf = ld4(vc + (t + 1) * HW + px);
      acc += rf * cm[t];
    }
    st4(out + ((size_t)b * 257 + 128 + cc * 8 + c) * HW + px, acc);
  }
}

extern "C" void kernel_launch(void* const* d_in, const int* in_sizes, int n_in,
                              void* d_out, int out_size, void* d_ws, size_t ws_size,
                              hipStream_t stream) {
  const float* values = (const float*)d_in[0];
  const float* tvmap  = (const float*)d_in[1];
  const float* rvmaps = (const float*)d_in[2];
  float* out = (float*)d_out;
  float* ws  = (float*)d_ws;

  hipLaunchKernelGGL(mask_kernel, dim3(512), dim3(256), 0, stream,
                     tvmap, rvmaps, ws);
  hipLaunchKernelGGL(gs_kernel, dim3(512), dim3(256), 0, stream,
                     values, ws);
  hipLaunchKernelGGL(out_kernel, dim3(512), dim3(256), 0, stream,
                     values, ws, out);
}